// Round 13
// baseline (541.357 us; speedup 1.0000x reference)
//
#include <hip/hip_runtime.h>
#include <hip/hip_bf16.h>
#include <math.h>

#define N1 60000
#define N2 50000
#define DIM 128
#define NREL 16
#define NB 4
#define LCOM 100
#define LPAD 112  // LCOM padded to 7x16 for MFMA N-tiles
#define NPART 8   // = #XCDs; blockIdx%8 -> XCD round-robin
#define NC 64     // edge-chunks per graph (slice count; must match hist & scatter)

typedef __attribute__((ext_vector_type(8))) short short8;
typedef __attribute__((ext_vector_type(4))) float f32x4;
typedef __attribute__((ext_vector_type(4))) _Float16 half4;
typedef __attribute__((ext_vector_type(8))) _Float16 half8;

__device__ __forceinline__ float bf2f(unsigned short u) {
    union { unsigned int i; float f; } c; c.i = ((unsigned int)u) << 16; return c.f;
}
__device__ __forceinline__ unsigned short f2bf(float f) {
    union { float f; unsigned int i; } c; c.f = f;
    unsigned int r = c.i + 0x7FFF + ((c.i >> 16) & 1);  // RNE
    return (unsigned short)(r >> 16);
}
__device__ __forceinline__ void split8(float4 a, float4 b, short8& h, short8& l) {
    float f[8] = {a.x, a.y, a.z, a.w, b.x, b.y, b.z, b.w};
#pragma unroll
    for (int j = 0; j < 8; j++) {
        unsigned short hh = f2bf(f[j]);
        h[j] = (short)hh;
        l[j] = (short)f2bf(f[j] - bf2f(hh));
    }
}

// ---------------- prelude: ATOMIC-FREE slice histograms ∪ weight prep ∪ emb cast ----------------
__global__ __launch_bounds__(256) void k_prelude(
        const int* __restrict__ ei1, int E1, int* __restrict__ degs1,
        const int* __restrict__ ei2, int E2, int* __restrict__ degs2,
        const float* __restrict__ root1, const float* __restrict__ basis1,
        unsigned short* __restrict__ Wh1, unsigned short* __restrict__ Wl1,
        const float* __restrict__ root2, const float* __restrict__ basis2,
        unsigned short* __restrict__ Wh2, unsigned short* __restrict__ Wl2, int PB,
        const float* __restrict__ emb, _Float16* __restrict__ embh, int n4) {
    __shared__ int hist[7500];
    int b = blockIdx.x;
    const int HB = NPART * NC;  // 512 hist blocks per graph
    if (b < 2 * HB) {
        int isg2 = b >= HB;
        int bb = isg2 ? b - HB : b;
        int p = bb & (NPART - 1);   // partition -> XCD (round-robin)
        int c = bb >> 3;            // edge chunk 0..NC-1
        const int* dsts = isg2 ? ei2 + E2 : ei1 + E1;
        int E = isg2 ? E2 : E1;
        int N = isg2 ? N2 : N1;
        int* degs = isg2 ? degs2 : degs1;
        const int W = (N + NPART - 1) / NPART;  // 7500 / 6250
        int lo = p * W, hi = min(lo + W, N);
        int span = hi - lo;
        for (int i = threadIdx.x; i < span; i += 256) hist[i] = 0;
        __syncthreads();
        int chunk = (E + NC - 1) / NC;
        int e0 = c * chunk, e1 = min(e0 + chunk, E);
        for (int base = e0; base < e1; base += 1024) {
            int d[4]; bool ok[4];
#pragma unroll
            for (int j = 0; j < 4; j++) {
                int e = base + threadIdx.x + j * 256;
                bool inb = e < e1;
                d[j] = inb ? __builtin_nontemporal_load(dsts + e) : -1;
                ok[j] = inb && d[j] >= lo && d[j] < hi;
            }
#pragma unroll
            for (int j = 0; j < 4; j++)
                if (ok[j]) atomicAdd(&hist[d[j] - lo], 1);  // LDS atomic: cheap
        }
        __syncthreads();
        int* slice = degs + (size_t)c * N + lo;
        for (int i = threadIdx.x; i < span; i += 256) slice[i] = hist[i];
    } else if (b < 2 * HB + PB) {
        int t = (b - 2 * HB) * 256 + threadIdx.x;
        if (t < 2 * 640 * 128) {
            int which = t >= 640 * 128;
            int tt = which ? t - 640 * 128 : t;
            const float* root = which ? root2 : root1;
            const float* basis = which ? basis2 : basis1;
            unsigned short* Wh = which ? Wh2 : Wh1;
            unsigned short* Wl = which ? Wl2 : Wl1;
            int k = tt >> 7, n = tt & 127;
            float v = (k < 128) ? root[k * 128 + n] : basis[(k - 128) * 128 + n];
            unsigned short h = f2bf(v);
            Wh[n * 640 + k] = h;
            Wl[n * 640 + k] = f2bf(v - bf2f(h));
        }
    } else {
        int i = (b - 2 * HB - PB) * 256 + threadIdx.x;
        if (i < n4) {
            float4 v = ((const float4*)emb)[i];
            half4 o = {(_Float16)v.x, (_Float16)v.y, (_Float16)v.z, (_Float16)v.w};
            ((half4*)embh)[i] = o;
        }
    }
}

// ---------------- merged hierarchical scan (p1 sums NC slices coalesced, emits compact deg) ----------------
__global__ __launch_bounds__(256) void k_scan_p1m(const int* __restrict__ degsA, int* __restrict__ degA,
                                                  int nA, int nbA, int* __restrict__ bsumA,
                                                  const int* __restrict__ degsB, int* __restrict__ degB,
                                                  int nB, int* __restrict__ bsumB) {
    __shared__ int red[256];
    const int* degs; int* deg; int n; int* bsum; int b;
    if ((int)blockIdx.x < nbA) { degs = degsA; deg = degA; n = nA; bsum = bsumA; b = blockIdx.x; }
    else { degs = degsB; deg = degB; n = nB; bsum = bsumB; b = blockIdx.x - nbA; }
    int base = b * 1024;
    int tid = threadIdx.x;
    int s = 0;
#pragma unroll
    for (int j = 0; j < 4; j++) {
        int i = base + tid + j * 256;
        if (i < n) {
            int v = 0;
            for (int c = 0; c < NC; c++) v += degs[(size_t)c * n + i];
            deg[i] = v;  // compact deg for p3m
            s += v;
        }
    }
    red[tid] = s;
    __syncthreads();
    for (int d = 128; d; d >>= 1) {
        if (tid < d) red[tid] += red[tid + d];
        __syncthreads();
    }
    if (tid == 0) bsum[b] = red[0];
}

__global__ __launch_bounds__(64) void k_scan_p2m(const int* __restrict__ bsumA, int* __restrict__ boffA,
                                                 int* __restrict__ offA, int nbA, int nA,
                                                 const int* __restrict__ bsumB, int* __restrict__ boffB,
                                                 int* __restrict__ offB, int nbB, int nB) {
    __shared__ int s[64];
    const int* bsum; int* boff; int* off; int nb; int n;
    if (blockIdx.x == 0) { bsum = bsumA; boff = boffA; off = offA; nb = nbA; n = nA; }
    else { bsum = bsumB; boff = boffB; off = offB; nb = nbB; n = nB; }
    int tid = threadIdx.x;
    int v = (tid < nb) ? bsum[tid] : 0;
    s[tid] = v;
    __syncthreads();
    for (int d = 1; d < 64; d <<= 1) {
        int t = (tid >= d) ? s[tid - d] : 0;
        __syncthreads();
        s[tid] += t;
        __syncthreads();
    }
    if (tid < nb) boff[tid] = s[tid] - v;
    if (tid == 63) off[n] = s[63];
}

// p3 writes off[], then converts degs slices IN PLACE to per-(c,node) base offsets.
__global__ __launch_bounds__(256) void k_scan_p3m(const int* __restrict__ inA, const int* __restrict__ boffA,
                                                  int* __restrict__ offA, int* __restrict__ sbA,
                                                  int nA, int nbA,
                                                  const int* __restrict__ inB, const int* __restrict__ boffB,
                                                  int* __restrict__ offB, int* __restrict__ sbB, int nB) {
    __shared__ int red[256];
    const int* in; const int* boff; int* off; int* sb; int n; int b;
    if ((int)blockIdx.x < nbA) { in = inA; boff = boffA; off = offA; sb = sbA; n = nA; b = blockIdx.x; }
    else { in = inB; boff = boffB; off = offB; sb = sbB; n = nB; b = blockIdx.x - nbA; }
    int base = b * 1024;
    int tid = threadIdx.x;
    int v[4];
    int s = 0;
#pragma unroll
    for (int j = 0; j < 4; j++) {
        int i = base + tid * 4 + j;
        v[j] = (i < n) ? in[i] : 0;
        s += v[j];
    }
    red[tid] = s;
    __syncthreads();
    for (int d = 1; d < 256; d <<= 1) {
        int t = (tid >= d) ? red[tid - d] : 0;
        __syncthreads();
        red[tid] += t;
        __syncthreads();
    }
    int run = boff[b] + red[tid] - s;
#pragma unroll
    for (int j = 0; j < 4; j++) {
        int i = base + tid * 4 + j;
        if (i < n) {
            off[i] = run;
            run += v[j];
        }
    }
    __syncthreads();
    for (int i = base + tid; i < min(base + 1024, n); i += 256) {
        int run2 = off[i];
        for (int c = 0; c < NC; c++) {
            size_t idx = (size_t)c * n + i;
            int t = sb[idx];
            sb[idx] = run2;
            run2 += t;
        }
    }
}

// ---------------- ATOMIC-FREE dst-partitioned scatter, both graphs ----------------
__global__ __launch_bounds__(256) void k_scat(const int* __restrict__ ei1, int E1,
                                              const int* __restrict__ sb1, int* __restrict__ elist1,
                                              const int* __restrict__ ei2, const int* __restrict__ et2,
                                              int E2, const int* __restrict__ sb2, int* __restrict__ elist2) {
    __shared__ int lcur[7500];
    int b = blockIdx.x;
    const int HB = NPART * NC;
    int isg2 = b >= HB;
    int bb = isg2 ? b - HB : b;
    int p = bb & (NPART - 1);
    int c = bb >> 3;
    const int* ei = isg2 ? ei2 : ei1;
    int E = isg2 ? E2 : E1;
    int N = isg2 ? N2 : N1;
    const int* sb = isg2 ? sb2 : sb1;
    int* elist = isg2 ? elist2 : elist1;
    const int W = (N + NPART - 1) / NPART;
    int lo = p * W, hi = min(lo + W, N);
    int span = hi - lo;
    for (int i = threadIdx.x; i < span; i += 256) lcur[i] = 0;
    __syncthreads();
    const int* sbc = sb + (size_t)c * N;
    int chunk = (E + NC - 1) / NC;
    int e0 = c * chunk, e1 = min(e0 + chunk, E);
    for (int base = e0; base < e1; base += 1024) {
        int d[4], sv[4], tv[4]; bool ok[4];
#pragma unroll
        for (int j = 0; j < 4; j++) {
            int e = base + threadIdx.x + j * 256;
            bool inb = e < e1;
            d[j] = inb ? __builtin_nontemporal_load(ei + E + e) : -1;
            sv[j] = inb ? __builtin_nontemporal_load(ei + e) : 0;
            tv[j] = (inb && isg2) ? __builtin_nontemporal_load(et2 + e) : 0;
            ok[j] = inb && d[j] >= lo && d[j] < hi;
        }
#pragma unroll
        for (int j = 0; j < 4; j++) {
            if (ok[j]) {
                int li = atomicAdd(&lcur[d[j] - lo], 1);  // LDS: low contention
                int pay = isg2 ? ((sv[j] << 4) | tv[j]) : sv[j];
                elist[sbc[d[j]] + li] = pay;              // plain store, exact position
            }
        }
    }
}

// ---------------- mix: concept_gather (4-deep row pipeline) ∪ tyw ----------------
__global__ __launch_bounds__(256) void k_mix(
        const _Float16* __restrict__ embh, const float* __restrict__ emb,
        const int* __restrict__ off1, const int* __restrict__ elist1,
        float* __restrict__ xg1, _Float16* __restrict__ xg1h, int CONC_B,
        const int* __restrict__ lc, const float* __restrict__ w,
        unsigned short* __restrict__ tyh, unsigned short* __restrict__ tyl) {
    int b = blockIdx.x;
    if (b < CONC_B) {
        int node = b * 4 + (threadIdx.x >> 6);
        int lane = threadIdx.x & 63;
        if (node >= N2) return;
        int quad = lane >> 4, d8 = (lane & 15) * 8;
        int s0 = off1[node], s1 = off1[node + 1];
        float acc[8] = {};
        int i = s0;
#define CLOAD(P) (*(const half8*)(embh + (size_t)(P) * DIM + d8))
        for (; i + 16 <= s1; i += 16) {
            int q0 = elist1[i + quad];
            int q1 = elist1[i + 4 + quad];
            int q2 = elist1[i + 8 + quad];
            int q3 = elist1[i + 12 + quad];
            half8 h0 = CLOAD(q0), h1 = CLOAD(q1), h2 = CLOAD(q2), h3 = CLOAD(q3);
#pragma unroll
            for (int j = 0; j < 8; j++) acc[j] += (float)h0[j] + (float)h1[j];
#pragma unroll
            for (int j = 0; j < 8; j++) acc[j] += (float)h2[j] + (float)h3[j];
        }
        if (i + 8 <= s1) {
            int q0 = elist1[i + quad];
            int q1 = elist1[i + 4 + quad];
            half8 h0 = CLOAD(q0), h1 = CLOAD(q1);
#pragma unroll
            for (int j = 0; j < 8; j++) acc[j] += (float)h0[j] + (float)h1[j];
            i += 8;
        }
        if (i + 4 <= s1) {
            int q0 = elist1[i + quad];
            half8 h0 = CLOAD(q0);
#pragma unroll
            for (int j = 0; j < 8; j++) acc[j] += (float)h0[j];
            i += 4;
        }
        if (i < s1) {
            int e = i + quad;
            bool ok = e < s1;
            int q0 = elist1[ok ? e : i];
            half8 h0 = CLOAD(q0);
            if (ok) {
#pragma unroll
                for (int j = 0; j < 8; j++) acc[j] += (float)h0[j];
            }
        }
#undef CLOAD
#pragma unroll
        for (int j = 0; j < 8; j++) {
            acc[j] += __shfl_xor(acc[j], 16, 64);
            acc[j] += __shfl_xor(acc[j], 32, 64);
        }
        if (quad == 0) {
            float inv = 1.0f / (float)max(s1 - s0, 1);
            const float* ep = emb + (size_t)node * DIM + d8;
            float4 e0 = *(const float4*)(ep);
            float4 e1 = *(const float4*)(ep + 4);
            float o[8];
            o[0] = fmaxf(e0.x + acc[0] * inv, 0.f);
            o[1] = fmaxf(e0.y + acc[1] * inv, 0.f);
            o[2] = fmaxf(e0.z + acc[2] * inv, 0.f);
            o[3] = fmaxf(e0.w + acc[3] * inv, 0.f);
            o[4] = fmaxf(e1.x + acc[4] * inv, 0.f);
            o[5] = fmaxf(e1.y + acc[5] * inv, 0.f);
            o[6] = fmaxf(e1.z + acc[6] * inv, 0.f);
            o[7] = fmaxf(e1.w + acc[7] * inv, 0.f);
            float4 w0 = {o[0], o[1], o[2], o[3]};
            float4 w1 = {o[4], o[5], o[6], o[7]};
            *(float4*)(xg1 + (size_t)node * DIM + d8) = w0;
            *(float4*)(xg1 + (size_t)node * DIM + d8 + 4) = w1;
            half8 oh;
#pragma unroll
            for (int j = 0; j < 8; j++) oh[j] = (_Float16)o[j];
            *(half8*)(xg1h + (size_t)node * DIM + d8) = oh;
        }
    } else {
        if (threadIdx.x >= 64) return;
        int l = b - CONC_B;
        int lane = threadIdx.x;
        int d0 = lane * 2;
        if (l >= LCOM) {
            ushort2 z = {0, 0};
            *(ushort2*)(tyh + (size_t)l * 128 + d0) = z;
            *(ushort2*)(tyl + (size_t)l * 128 + d0) = z;
            return;
        }
        int row = lc[l];
        int s0 = off1[row], s1 = off1[row + 1];
        float2 acc = {0.f, 0.f};
        for (int i = s0; i < s1; i++) {
            int s = elist1[i];
            float2 v = *(const float2*)(emb + (size_t)s * DIM + lane * 2);
            acc.x += v.x; acc.y += v.y;
        }
        float inv = 1.0f / (float)max(s1 - s0, 1);
        float2 e = *(const float2*)(emb + (size_t)row * DIM + lane * 2);
        float v0 = fmaxf(e.x + acc.x * inv, 0.f) * w[d0];
        float v1 = fmaxf(e.y + acc.y * inv, 0.f) * w[d0 + 1];
        unsigned short h0 = f2bf(v0), h1 = f2bf(v1);
        ushort2 hh = {h0, h1};
        ushort2 ll = {f2bf(v0 - bf2f(h0)), f2bf(v1 - bf2f(h1))};
        *(ushort2*)(tyh + (size_t)l * 128 + d0) = hh;
        *(ushort2*)(tyl + (size_t)l * 128 + d0) = ll;
    }
}

// ---------------- rgcn aggregation: fp16 gather, 4-deep row pipeline, fp16 agg output ----------------
__global__ __launch_bounds__(256) void k_rgcn_gather(const _Float16* __restrict__ xh,
                                                     const int* __restrict__ off,
                                                     const int* __restrict__ elist,
                                                     const float* __restrict__ comp,
                                                     _Float16* __restrict__ aggh, int n) {
    __shared__ float scomp[NREL * NB];
    __shared__ float nrmlds[4][NREL];
    if (threadIdx.x < NREL * NB) scomp[threadIdx.x] = comp[threadIdx.x];
    __syncthreads();
    int nb = threadIdx.x >> 6;
    int node = blockIdx.x * 4 + nb;
    int lane = threadIdx.x & 63;
    if (node >= n) return;
    int s0 = off[node], s1 = off[node + 1];
    // prescan: byte-packed per-type counts, lane-parallel then shfl-reduce
    unsigned long long c0 = 0, c1 = 0;
    for (int i = s0 + lane; i < s1; i += 64) {
        int t = elist[i] & 15;
        if (t < 8) c0 += 1ull << (8 * t); else c1 += 1ull << (8 * (t - 8));
    }
#pragma unroll
    for (int o = 32; o; o >>= 1) {
        c0 += __shfl_xor(c0, o, 64);
        c1 += __shfl_xor(c1, o, 64);
    }
    if (lane < NREL) {
        unsigned int c = (lane < 8) ? (unsigned int)((c0 >> (8 * lane)) & 255)
                                    : (unsigned int)((c1 >> (8 * (lane - 8))) & 255);
        nrmlds[nb][lane] = 1.0f / (float)max(c, 1u);
    }
    // same-wave LDS write->read: no barrier needed
    int quad = lane >> 4, d8 = (lane & 15) * 8;
    float a[4][8] = {};
#define RGLOAD(P) (*(const half8*)(xh + (size_t)((P) >> 4) * DIM + d8))
#define RGC(P, HV, GATE)                                                       \
    {                                                                          \
        int t_ = (P) & 15;                                                     \
        float nr_ = nrmlds[nb][t_] * (GATE);                                   \
        float4 cf_ = *(const float4*)(scomp + t_ * 4);                         \
        float c0_ = cf_.x * nr_, c1_ = cf_.y * nr_;                            \
        float c2_ = cf_.z * nr_, c3_ = cf_.w * nr_;                            \
        _Pragma("unroll")                                                      \
        for (int j = 0; j < 8; j++) {                                          \
            float v_ = (float)HV[j];                                           \
            a[0][j] = fmaf(c0_, v_, a[0][j]);                                  \
            a[1][j] = fmaf(c1_, v_, a[1][j]);                                  \
            a[2][j] = fmaf(c2_, v_, a[2][j]);                                  \
            a[3][j] = fmaf(c3_, v_, a[3][j]);                                  \
        }                                                                      \
    }
    int i = s0;
    for (; i + 16 <= s1; i += 16) {
        int p0 = elist[i + quad];
        int p1 = elist[i + 4 + quad];
        int p2 = elist[i + 8 + quad];
        int p3 = elist[i + 12 + quad];
        half8 h0 = RGLOAD(p0), h1 = RGLOAD(p1), h2 = RGLOAD(p2), h3 = RGLOAD(p3);
        RGC(p0, h0, 1.0f);
        RGC(p1, h1, 1.0f);
        RGC(p2, h2, 1.0f);
        RGC(p3, h3, 1.0f);
    }
    if (i + 8 <= s1) {
        int p0 = elist[i + quad];
        int p1 = elist[i + 4 + quad];
        half8 h0 = RGLOAD(p0), h1 = RGLOAD(p1);
        RGC(p0, h0, 1.0f);
        RGC(p1, h1, 1.0f);
        i += 8;
    }
    if (i + 4 <= s1) {
        int p0 = elist[i + quad];
        half8 h0 = RGLOAD(p0);
        RGC(p0, h0, 1.0f);
        i += 4;
    }
    if (i < s1) {
        int e = i + quad;
        bool ok = e < s1;
        int p0 = elist[ok ? e : i];
        half8 h0 = RGLOAD(p0);
        RGC(p0, h0, ok ? 1.0f : 0.0f);
    }
#undef RGC
#undef RGLOAD
#pragma unroll
    for (int bb = 0; bb < 4; bb++)
#pragma unroll
        for (int j = 0; j < 8; j++) {
            a[bb][j] += __shfl_xor(a[bb][j], 16, 64);
            a[bb][j] += __shfl_xor(a[bb][j], 32, 64);
        }
    if (quad == 0) {
        _Float16* o = aggh + (size_t)node * (NB * DIM) + d8;
#pragma unroll
        for (int bb = 0; bb < 4; bb++) {
            half8 hv;
#pragma unroll
            for (int j = 0; j < 8; j++) hv[j] = (_Float16)a[bb][j];
            *(half8*)(o + bb * DIM) = hv;
        }
    }
}

// ---------------- split-precision MFMA GEMM (fp32 x, fp16 agg; optional fp16 shadow out) ----------------
#define LDSK 40
__global__ __launch_bounds__(256) void k_gemm(const float* __restrict__ x,
                                              const _Float16* __restrict__ aggh,
                                              const unsigned short* __restrict__ Wh,
                                              const unsigned short* __restrict__ Wl,
                                              const float* __restrict__ bias,
                                              float* __restrict__ out,
                                              _Float16* __restrict__ out_h, int relu) {
    __shared__ __align__(16) short Ah[128 * LDSK];
    __shared__ __align__(16) short Al[128 * LDSK];
    __shared__ __align__(16) short Bh[128 * LDSK];
    __shared__ __align__(16) short Bl[128 * LDSK];
    int tid = threadIdx.x;
    int lane = tid & 63, wid = tid >> 6;
    int wave_m = wid >> 1, wave_n = wid & 1;
    int l15 = lane & 15, quad = lane >> 4;
    int row0 = blockIdx.x * 128;

    int srow = tid >> 1, skh = (tid & 1) * 16;

    f32x4 acc[4][4] = {};
    for (int k0 = 0; k0 < 640; k0 += 32) {
        {
            int rg = row0 + srow;
            float4 q0 = {0, 0, 0, 0}, q1 = q0, q2 = q0, q3 = q0;
            if (rg < N2) {
                if (k0 < 128) {
                    const float* src = x + (size_t)rg * 128 + k0 + skh;
                    q0 = *(const float4*)(src + 0);
                    q1 = *(const float4*)(src + 4);
                    q2 = *(const float4*)(src + 8);
                    q3 = *(const float4*)(src + 12);
                } else {
                    const _Float16* src = aggh + (size_t)rg * 512 + (k0 - 128) + skh;
                    half8 ha = *(const half8*)(src);
                    half8 hb = *(const half8*)(src + 8);
                    q0 = {(float)ha[0], (float)ha[1], (float)ha[2], (float)ha[3]};
                    q1 = {(float)ha[4], (float)ha[5], (float)ha[6], (float)ha[7]};
                    q2 = {(float)hb[0], (float)hb[1], (float)hb[2], (float)hb[3]};
                    q3 = {(float)hb[4], (float)hb[5], (float)hb[6], (float)hb[7]};
                }
            }
            short8 h0, l0, h1, l1;
            split8(q0, q1, h0, l0);
            split8(q2, q3, h1, l1);
            *(short8*)(&Ah[srow * LDSK + skh]) = h0;
            *(short8*)(&Ah[srow * LDSK + skh + 8]) = h1;
            *(short8*)(&Al[srow * LDSK + skh]) = l0;
            *(short8*)(&Al[srow * LDSK + skh + 8]) = l1;
        }
        {
            const unsigned short* sh = Wh + (size_t)srow * 640 + k0 + skh;
            const unsigned short* sl = Wl + (size_t)srow * 640 + k0 + skh;
            *(short8*)(&Bh[srow * LDSK + skh]) = *(const short8*)(sh);
            *(short8*)(&Bh[srow * LDSK + skh + 8]) = *(const short8*)(sh + 8);
            *(short8*)(&Bl[srow * LDSK + skh]) = *(const short8*)(sl);
            *(short8*)(&Bl[srow * LDSK + skh + 8]) = *(const short8*)(sl + 8);
        }
        __syncthreads();
        short8 ah[4], al[4], bh[4], bl[4];
#pragma unroll
        for (int i = 0; i < 4; i++) {
            int ro = (wave_m * 64 + i * 16 + l15) * LDSK + quad * 8;
            ah[i] = *(const short8*)(&Ah[ro]);
            al[i] = *(const short8*)(&Al[ro]);
        }
#pragma unroll
        for (int j = 0; j < 4; j++) {
            int ro = (wave_n * 64 + j * 16 + l15) * LDSK + quad * 8;
            bh[j] = *(const short8*)(&Bh[ro]);
            bl[j] = *(const short8*)(&Bl[ro]);
        }
#pragma unroll
        for (int i = 0; i < 4; i++)
#pragma unroll
            for (int j = 0; j < 4; j++) {
                acc[i][j] = __builtin_amdgcn_mfma_f32_16x16x32_bf16(al[i], bh[j], acc[i][j], 0, 0, 0);
                acc[i][j] = __builtin_amdgcn_mfma_f32_16x16x32_bf16(ah[i], bl[j], acc[i][j], 0, 0, 0);
                acc[i][j] = __builtin_amdgcn_mfma_f32_16x16x32_bf16(ah[i], bh[j], acc[i][j], 0, 0, 0);
            }
        __syncthreads();
    }
#pragma unroll
    for (int j = 0; j < 4; j++) {
        int gcol = wave_n * 64 + j * 16 + l15;
        float bv = bias[gcol];
#pragma unroll
        for (int i = 0; i < 4; i++) {
            int grow_base = row0 + wave_m * 64 + i * 16 + quad * 4;
#pragma unroll
            for (int r = 0; r < 4; r++) {
                int grow = grow_base + r;
                if (grow >= N2) continue;
                float v = acc[i][j][r] + bv;
                if (relu) v = fmaxf(v, 0.f);
                out[(size_t)grow * 128 + gcol] = v;
                if (out_h) out_h[(size_t)grow * 128 + gcol] = (_Float16)v;
            }
        }
    }
}

// ---------------- logits + softmax: MFMA, no LDS ----------------
__global__ __launch_bounds__(256) void k_logits(const float* __restrict__ h2,
                                                const unsigned short* __restrict__ tyh,
                                                const unsigned short* __restrict__ tyl,
                                                float* __restrict__ out, int M) {
    int wid = threadIdx.x >> 6, lane = threadIdx.x & 63;
    int l15 = lane & 15, quad = lane >> 4;
    int row0w = blockIdx.x * 64 + wid * 16;
    int arow = min(row0w + l15, M - 1);
    f32x4 acc[7] = {};
#pragma unroll
    for (int k0 = 0; k0 < 128; k0 += 32) {
        const float* ap = h2 + (size_t)arow * 128 + k0 + quad * 8;
        float4 q0 = *(const float4*)(ap);
        float4 q1 = *(const float4*)(ap + 4);
        short8 ah, al;
        split8(q0, q1, ah, al);
#pragma unroll
        for (int j = 0; j < 7; j++) {
            size_t bo = (size_t)(j * 16 + l15) * 128 + k0 + quad * 8;
            short8 bh = *(const short8*)(tyh + bo);
            short8 bl = *(const short8*)(tyl + bo);
            acc[j] = __builtin_amdgcn_mfma_f32_16x16x32_bf16(al, bh, acc[j], 0, 0, 0);
            acc[j] = __builtin_amdgcn_mfma_f32_16x16x32_bf16(ah, bl, acc[j], 0, 0, 0);
            acc[j] = __builtin_amdgcn_mfma_f32_16x16x32_bf16(ah, bh, acc[j], 0, 0, 0);
        }
    }
    bool v6 = (l15 < LCOM - 96);
#pragma unroll
    for (int r = 0; r < 4; r++) {
        int grow = row0w + quad * 4 + r;
        float m = -INFINITY;
#pragma unroll
        for (int j = 0; j < 6; j++) m = fmaxf(m, acc[j][r]);
        if (v6) m = fmaxf(m, acc[6][r]);
        m = fmaxf(m, __shfl_xor(m, 8, 64));
        m = fmaxf(m, __shfl_xor(m, 4, 64));
        m = fmaxf(m, __shfl_xor(m, 2, 64));
        m = fmaxf(m, __shfl_xor(m, 1, 64));
        float e[7];
        float s = 0.f;
#pragma unroll
        for (int j = 0; j < 6; j++) { e[j] = __expf(acc[j][r] - m); s += e[j]; }
        e[6] = v6 ? __expf(acc[6][r] - m) : 0.f;
        s += e[6];
        s += __shfl_xor(s, 8, 64);
        s += __shfl_xor(s, 4, 64);
        s += __shfl_xor(s, 2, 64);
        s += __shfl_xor(s, 1, 64);
        float inv = 1.0f / s;
        if (grow < M) {
#pragma unroll
            for (int j = 0; j < 6; j++) out[(size_t)grow * LCOM + j * 16 + l15] = e[j] * inv;
            if (v6) out[(size_t)grow * LCOM + 96 + l15] = e[6] * inv;
        }
    }
}

extern "C" void kernel_launch(void* const* d_in, const int* in_sizes, int n_in,
                              void* d_out, int out_size, void* d_ws, size_t ws_size,
                              hipStream_t stream) {
    const int* ei2 = (const int*)d_in[0];
    const int* et2 = (const int*)d_in[1];
    const int* ei1 = (const int*)d_in[2];
    const int* lc = (const int*)d_in[3];
    const float* emb = (const float*)d_in[4];
    const float* basis1 = (const float*)d_in[5];
    const float* comp1 = (const float*)d_in[6];
    const float* root1 = (const float*)d_in[7];
    const float* bias1 = (const float*)d_in[8];
    const float* basis2 = (const float*)d_in[9];
    const float* comp2 = (const float*)d_in[10];
    const float* root2 = (const float*)d_in[11];
    const float* bias2 = (const float*)d_in[12];
    const float* wts = (const float*)d_in[13];
    float* out = (float*)d_out;
    int E2 = in_sizes[0] / 2, E1 = in_sizes[2] / 2;

    float* ws = (float*)d_ws;
    float* xg1 = ws;                          // 6,400,000 f (reused as h2)
    float* h1 = xg1 + 6400000;                // 6,400,000 f (first half aliased as xg1_h)
    float* agg = h1 + 6400000;                // 25,600,000 f (head: deg slices pre-scatter, then fp16 agg)
    _Float16* emb_h = (_Float16*)(agg + 25600000);  // 7,680,000 h (first 6.4M aliased as h1_h)
    unsigned short* tyh = (unsigned short*)(emb_h + 7680000);  // 14,336
    unsigned short* tyl = tyh + LPAD * 128;                    // 14,336
    unsigned short* Wh1 = tyl + LPAD * 128;   // 81,920 each
    unsigned short* Wl1 = Wh1 + 81920;
    unsigned short* Wh2 = Wl1 + 81920;
    unsigned short* Wl2 = Wh2 + 81920;
    int* ipool = (int*)(Wl2 + 81920);
    int* deg1 = ipool;                        // 60,000 (compact, written by p1m)
    int* deg2 = deg1 + 60000;                 // 50,000
    int* off1 = deg2 + 50000;                 // 60,001
    int* elist1 = off1 + 60001;               // 800,000
    int* off2 = elist1 + 800000;              // 50,001
    int* elist2 = off2 + 50001;               // 800,000
    int* bsum1 = elist2 + 800000;             // 64
    int* boff1 = bsum1 + 64;
    int* bsum2 = boff1 + 64;
    int* boff2 = bsum2 + 64;
    int* degs1 = (int*)agg;                   // NC*60,000 slice hist -> slice bases
    int* degs2 = degs1 + NC * N1;             // NC*50,000 (28.2 MB, dead after k_scat)
    _Float16* agg_h = (_Float16*)agg;         // fp16 agg (25.6 MB), written by gather after scat
    _Float16* xg1_h = (_Float16*)h1;          // alias: gather1 consumes xg1_h before gemm1 writes h1
    _Float16* h1_h = emb_h;                   // alias: emb_h consumed by k_mix before gemm1 writes
    float* h2 = xg1;                          // alias: xg1 dead after gemm1

    const int NB1 = (N1 + 1023) / 1024;       // 59
    const int NB2 = (N2 + 1023) / 1024;       // 49
    const int PB = (2 * 640 * 128) / 256;     // 640
    const int CB = (N1 * DIM / 4 + 255) / 256;  // 7500
    const int CONC_B = (N2 + 3) / 4;          // 12500

    // 1) prelude: atomic-free slice hists (dispatch first) ∪ weight prep ∪ emb cast
    k_prelude<<<2 * NPART * NC + PB + CB, 256, 0, stream>>>(
        ei1, E1, degs1, ei2, E2, degs2,
        root1, basis1, Wh1, Wl1, root2, basis2, Wh2, Wl2, PB,
        emb, emb_h, N1 * DIM / 4);

    // 2-4) merged scans (p1 sums slices -> compact deg; p3 writes off + converts slices to bases)
    k_scan_p1m<<<NB1 + NB2, 256, 0, stream>>>(degs1, deg1, N1, NB1, bsum1,
                                              degs2, deg2, N2, bsum2);
    k_scan_p2m<<<2, 64, 0, stream>>>(bsum1, boff1, off1, NB1, N1, bsum2, boff2, off2, NB2, N2);
    k_scan_p3m<<<NB1 + NB2, 256, 0, stream>>>(deg1, boff1, off1, degs1, N1, NB1,
                                              deg2, boff2, off2, degs2, N2);

    // 5) atomic-free scatter, both graphs (exact positions, plain stores)
    k_scat<<<2 * NPART * NC, 256, 0, stream>>>(ei1, E1, degs1, elist1,
                                               ei2, et2, E2, degs2, elist2);

    // 6) mix: concept ∪ tyw
    k_mix<<<CONC_B + LPAD, 256, 0, stream>>>(
        emb_h, emb, off1, elist1, xg1, xg1_h, CONC_B,
        lc, wts, tyh, tyl);

    // 7-8) rgcn layer 1 (fp16 agg)
    k_rgcn_gather<<<CONC_B, 256, 0, stream>>>(xg1_h, off2, elist2, comp1, agg_h, N2);
    k_gemm<<<(N2 + 127) / 128, 256, 0, stream>>>(xg1, agg_h, Wh1, Wl1, bias1, h1, h1_h, 1);

    // 9-10) rgcn layer 2 (fp16 agg)
    k_rgcn_gather<<<CONC_B, 256, 0, stream>>>(h1_h, off2, elist2, comp2, agg_h, N2);
    k_gemm<<<(N2 + 127) / 128, 256, 0, stream>>>(h1, agg_h, Wh2, Wl2, bias2, h2, (_Float16*)nullptr, 0);

    // 11) logits + softmax
    k_logits<<<(N2 + 63) / 64, 256, 0, stream>>>(h2, tyh, tyl, out, N2);
}

// Round 14
// 527.238 us; speedup vs baseline: 1.0268x; 1.0268x over previous
//
#include <hip/hip_runtime.h>
#include <hip/hip_bf16.h>
#include <math.h>

#define N1 60000
#define N2 50000
#define DIM 128
#define NREL 16
#define NB 4
#define LCOM 100
#define LPAD 112  // LCOM padded to 7x16 for MFMA N-tiles
#define NPART 8   // = #XCDs; blockIdx%8 -> XCD round-robin
#define NC 64     // edge-chunks per graph (slice count; must match hist & scatter)

typedef __attribute__((ext_vector_type(8))) short short8;
typedef __attribute__((ext_vector_type(4))) float f32x4;
typedef __attribute__((ext_vector_type(4))) _Float16 half4;
typedef __attribute__((ext_vector_type(8))) _Float16 half8;

__device__ __forceinline__ float bf2f(unsigned short u) {
    union { unsigned int i; float f; } c; c.i = ((unsigned int)u) << 16; return c.f;
}
__device__ __forceinline__ unsigned short f2bf(float f) {
    union { float f; unsigned int i; } c; c.f = f;
    unsigned int r = c.i + 0x7FFF + ((c.i >> 16) & 1);  // RNE
    return (unsigned short)(r >> 16);
}
__device__ __forceinline__ void split8(float4 a, float4 b, short8& h, short8& l) {
    float f[8] = {a.x, a.y, a.z, a.w, b.x, b.y, b.z, b.w};
#pragma unroll
    for (int j = 0; j < 8; j++) {
        unsigned short hh = f2bf(f[j]);
        h[j] = (short)hh;
        l[j] = (short)f2bf(f[j] - bf2f(hh));
    }
}

// ---------------- prelude: ATOMIC-FREE slice histograms ∪ weight prep ∪ emb cast ----------------
__global__ __launch_bounds__(256) void k_prelude(
        const int* __restrict__ ei1, int E1, int* __restrict__ degs1,
        const int* __restrict__ ei2, int E2, int* __restrict__ degs2,
        const float* __restrict__ root1, const float* __restrict__ basis1,
        unsigned short* __restrict__ Wh1, unsigned short* __restrict__ Wl1,
        const float* __restrict__ root2, const float* __restrict__ basis2,
        unsigned short* __restrict__ Wh2, unsigned short* __restrict__ Wl2, int PB,
        const float* __restrict__ emb, _Float16* __restrict__ embh, int n4) {
    __shared__ int hist[7500];
    int b = blockIdx.x;
    const int HB = NPART * NC;  // 512 hist blocks per graph
    if (b < 2 * HB) {
        int isg2 = b >= HB;
        int bb = isg2 ? b - HB : b;
        int p = bb & (NPART - 1);   // partition -> XCD (round-robin)
        int c = bb >> 3;            // edge chunk 0..NC-1
        const int* dsts = isg2 ? ei2 + E2 : ei1 + E1;
        int E = isg2 ? E2 : E1;
        int N = isg2 ? N2 : N1;
        int* degs = isg2 ? degs2 : degs1;
        const int W = (N + NPART - 1) / NPART;  // 7500 / 6250
        int lo = p * W, hi = min(lo + W, N);
        int span = hi - lo;
        for (int i = threadIdx.x; i < span; i += 256) hist[i] = 0;
        __syncthreads();
        int chunk = (E + NC - 1) / NC;
        int e0 = c * chunk, e1 = min(e0 + chunk, E);
        for (int base = e0; base < e1; base += 1024) {
            int d[4]; bool ok[4];
#pragma unroll
            for (int j = 0; j < 4; j++) {
                int e = base + threadIdx.x + j * 256;
                bool inb = e < e1;
                d[j] = inb ? __builtin_nontemporal_load(dsts + e) : -1;
                ok[j] = inb && d[j] >= lo && d[j] < hi;
            }
#pragma unroll
            for (int j = 0; j < 4; j++)
                if (ok[j]) atomicAdd(&hist[d[j] - lo], 1);  // LDS atomic: cheap
        }
        __syncthreads();
        int* slice = degs + (size_t)c * N + lo;
        for (int i = threadIdx.x; i < span; i += 256) slice[i] = hist[i];
    } else if (b < 2 * HB + PB) {
        int t = (b - 2 * HB) * 256 + threadIdx.x;
        if (t < 2 * 640 * 128) {
            int which = t >= 640 * 128;
            int tt = which ? t - 640 * 128 : t;
            const float* root = which ? root2 : root1;
            const float* basis = which ? basis2 : basis1;
            unsigned short* Wh = which ? Wh2 : Wh1;
            unsigned short* Wl = which ? Wl2 : Wl1;
            int k = tt >> 7, n = tt & 127;
            float v = (k < 128) ? root[k * 128 + n] : basis[(k - 128) * 128 + n];
            unsigned short h = f2bf(v);
            Wh[n * 640 + k] = h;
            Wl[n * 640 + k] = f2bf(v - bf2f(h));
        }
    } else {
        int i = (b - 2 * HB - PB) * 256 + threadIdx.x;
        if (i < n4) {
            float4 v = ((const float4*)emb)[i];
            half4 o = {(_Float16)v.x, (_Float16)v.y, (_Float16)v.z, (_Float16)v.w};
            ((half4*)embh)[i] = o;
        }
    }
}

// ---------------- merged hierarchical scan (p1 sums NC slices coalesced, emits compact deg) ----------------
__global__ __launch_bounds__(256) void k_scan_p1m(const int* __restrict__ degsA, int* __restrict__ degA,
                                                  int nA, int nbA, int* __restrict__ bsumA,
                                                  const int* __restrict__ degsB, int* __restrict__ degB,
                                                  int nB, int* __restrict__ bsumB) {
    __shared__ int red[256];
    const int* degs; int* deg; int n; int* bsum; int b;
    if ((int)blockIdx.x < nbA) { degs = degsA; deg = degA; n = nA; bsum = bsumA; b = blockIdx.x; }
    else { degs = degsB; deg = degB; n = nB; bsum = bsumB; b = blockIdx.x - nbA; }
    int base = b * 1024;
    int tid = threadIdx.x;
    int s = 0;
#pragma unroll
    for (int j = 0; j < 4; j++) {
        int i = base + tid + j * 256;
        if (i < n) {
            int v = 0;
            for (int c = 0; c < NC; c++) v += degs[(size_t)c * n + i];
            deg[i] = v;  // compact deg for p3m
            s += v;
        }
    }
    red[tid] = s;
    __syncthreads();
    for (int d = 128; d; d >>= 1) {
        if (tid < d) red[tid] += red[tid + d];
        __syncthreads();
    }
    if (tid == 0) bsum[b] = red[0];
}

__global__ __launch_bounds__(64) void k_scan_p2m(const int* __restrict__ bsumA, int* __restrict__ boffA,
                                                 int* __restrict__ offA, int nbA, int nA,
                                                 const int* __restrict__ bsumB, int* __restrict__ boffB,
                                                 int* __restrict__ offB, int nbB, int nB) {
    __shared__ int s[64];
    const int* bsum; int* boff; int* off; int nb; int n;
    if (blockIdx.x == 0) { bsum = bsumA; boff = boffA; off = offA; nb = nbA; n = nA; }
    else { bsum = bsumB; boff = boffB; off = offB; nb = nbB; n = nB; }
    int tid = threadIdx.x;
    int v = (tid < nb) ? bsum[tid] : 0;
    s[tid] = v;
    __syncthreads();
    for (int d = 1; d < 64; d <<= 1) {
        int t = (tid >= d) ? s[tid - d] : 0;
        __syncthreads();
        s[tid] += t;
        __syncthreads();
    }
    if (tid < nb) boff[tid] = s[tid] - v;
    if (tid == 63) off[n] = s[63];
}

// p3 writes off[], then converts degs slices IN PLACE to per-(c,node) base offsets.
__global__ __launch_bounds__(256) void k_scan_p3m(const int* __restrict__ inA, const int* __restrict__ boffA,
                                                  int* __restrict__ offA, int* __restrict__ sbA,
                                                  int nA, int nbA,
                                                  const int* __restrict__ inB, const int* __restrict__ boffB,
                                                  int* __restrict__ offB, int* __restrict__ sbB, int nB) {
    __shared__ int red[256];
    const int* in; const int* boff; int* off; int* sb; int n; int b;
    if ((int)blockIdx.x < nbA) { in = inA; boff = boffA; off = offA; sb = sbA; n = nA; b = blockIdx.x; }
    else { in = inB; boff = boffB; off = offB; sb = sbB; n = nB; b = blockIdx.x - nbA; }
    int base = b * 1024;
    int tid = threadIdx.x;
    int v[4];
    int s = 0;
#pragma unroll
    for (int j = 0; j < 4; j++) {
        int i = base + tid * 4 + j;
        v[j] = (i < n) ? in[i] : 0;
        s += v[j];
    }
    red[tid] = s;
    __syncthreads();
    for (int d = 1; d < 256; d <<= 1) {
        int t = (tid >= d) ? red[tid - d] : 0;
        __syncthreads();
        red[tid] += t;
        __syncthreads();
    }
    int run = boff[b] + red[tid] - s;
#pragma unroll
    for (int j = 0; j < 4; j++) {
        int i = base + tid * 4 + j;
        if (i < n) {
            off[i] = run;
            run += v[j];
        }
    }
    __syncthreads();
    for (int i = base + tid; i < min(base + 1024, n); i += 256) {
        int run2 = off[i];
        for (int c = 0; c < NC; c++) {
            size_t idx = (size_t)c * n + i;
            int t = sb[idx];
            sb[idx] = run2;
            run2 += t;
        }
    }
}

// ---------------- ATOMIC-FREE dst-partitioned scatter, both graphs ----------------
__global__ __launch_bounds__(256) void k_scat(const int* __restrict__ ei1, int E1,
                                              const int* __restrict__ sb1, int* __restrict__ elist1,
                                              const int* __restrict__ ei2, const int* __restrict__ et2,
                                              int E2, const int* __restrict__ sb2, int* __restrict__ elist2) {
    __shared__ int lcur[7500];
    int b = blockIdx.x;
    const int HB = NPART * NC;
    int isg2 = b >= HB;
    int bb = isg2 ? b - HB : b;
    int p = bb & (NPART - 1);
    int c = bb >> 3;
    const int* ei = isg2 ? ei2 : ei1;
    int E = isg2 ? E2 : E1;
    int N = isg2 ? N2 : N1;
    const int* sb = isg2 ? sb2 : sb1;
    int* elist = isg2 ? elist2 : elist1;
    const int W = (N + NPART - 1) / NPART;
    int lo = p * W, hi = min(lo + W, N);
    int span = hi - lo;
    for (int i = threadIdx.x; i < span; i += 256) lcur[i] = 0;
    __syncthreads();
    const int* sbc = sb + (size_t)c * N;
    int chunk = (E + NC - 1) / NC;
    int e0 = c * chunk, e1 = min(e0 + chunk, E);
    for (int base = e0; base < e1; base += 1024) {
        int d[4], sv[4], tv[4]; bool ok[4];
#pragma unroll
        for (int j = 0; j < 4; j++) {
            int e = base + threadIdx.x + j * 256;
            bool inb = e < e1;
            d[j] = inb ? __builtin_nontemporal_load(ei + E + e) : -1;
            sv[j] = inb ? __builtin_nontemporal_load(ei + e) : 0;
            tv[j] = (inb && isg2) ? __builtin_nontemporal_load(et2 + e) : 0;
            ok[j] = inb && d[j] >= lo && d[j] < hi;
        }
#pragma unroll
        for (int j = 0; j < 4; j++) {
            if (ok[j]) {
                int li = atomicAdd(&lcur[d[j] - lo], 1);  // LDS: low contention
                int pay = isg2 ? ((sv[j] << 4) | tv[j]) : sv[j];
                elist[sbc[d[j]] + li] = pay;              // plain store, exact position
            }
        }
    }
}

// ---------------- mix: concept_gather (4-deep row pipeline) ∪ tyw ----------------
__global__ __launch_bounds__(256) void k_mix(
        const _Float16* __restrict__ embh, const float* __restrict__ emb,
        const int* __restrict__ off1, const int* __restrict__ elist1,
        float* __restrict__ xg1, _Float16* __restrict__ xg1h, int CONC_B,
        const int* __restrict__ lc, const float* __restrict__ w,
        unsigned short* __restrict__ tyh, unsigned short* __restrict__ tyl) {
    int b = blockIdx.x;
    if (b < CONC_B) {
        int node = b * 4 + (threadIdx.x >> 6);
        int lane = threadIdx.x & 63;
        if (node >= N2) return;
        int quad = lane >> 4, d8 = (lane & 15) * 8;
        int s0 = off1[node], s1 = off1[node + 1];
        float acc[8] = {};
        int i = s0;
#define CLOAD(P) (*(const half8*)(embh + (size_t)(P) * DIM + d8))
        for (; i + 16 <= s1; i += 16) {
            int q0 = elist1[i + quad];
            int q1 = elist1[i + 4 + quad];
            int q2 = elist1[i + 8 + quad];
            int q3 = elist1[i + 12 + quad];
            half8 h0 = CLOAD(q0), h1 = CLOAD(q1), h2 = CLOAD(q2), h3 = CLOAD(q3);
#pragma unroll
            for (int j = 0; j < 8; j++) acc[j] += (float)h0[j] + (float)h1[j];
#pragma unroll
            for (int j = 0; j < 8; j++) acc[j] += (float)h2[j] + (float)h3[j];
        }
        if (i + 8 <= s1) {
            int q0 = elist1[i + quad];
            int q1 = elist1[i + 4 + quad];
            half8 h0 = CLOAD(q0), h1 = CLOAD(q1);
#pragma unroll
            for (int j = 0; j < 8; j++) acc[j] += (float)h0[j] + (float)h1[j];
            i += 8;
        }
        if (i + 4 <= s1) {
            int q0 = elist1[i + quad];
            half8 h0 = CLOAD(q0);
#pragma unroll
            for (int j = 0; j < 8; j++) acc[j] += (float)h0[j];
            i += 4;
        }
        if (i < s1) {
            int e = i + quad;
            bool ok = e < s1;
            int q0 = elist1[ok ? e : i];
            half8 h0 = CLOAD(q0);
            if (ok) {
#pragma unroll
                for (int j = 0; j < 8; j++) acc[j] += (float)h0[j];
            }
        }
#undef CLOAD
#pragma unroll
        for (int j = 0; j < 8; j++) {
            acc[j] += __shfl_xor(acc[j], 16, 64);
            acc[j] += __shfl_xor(acc[j], 32, 64);
        }
        if (quad == 0) {
            float inv = 1.0f / (float)max(s1 - s0, 1);
            const float* ep = emb + (size_t)node * DIM + d8;
            float4 e0 = *(const float4*)(ep);
            float4 e1 = *(const float4*)(ep + 4);
            float o[8];
            o[0] = fmaxf(e0.x + acc[0] * inv, 0.f);
            o[1] = fmaxf(e0.y + acc[1] * inv, 0.f);
            o[2] = fmaxf(e0.z + acc[2] * inv, 0.f);
            o[3] = fmaxf(e0.w + acc[3] * inv, 0.f);
            o[4] = fmaxf(e1.x + acc[4] * inv, 0.f);
            o[5] = fmaxf(e1.y + acc[5] * inv, 0.f);
            o[6] = fmaxf(e1.z + acc[6] * inv, 0.f);
            o[7] = fmaxf(e1.w + acc[7] * inv, 0.f);
            float4 w0 = {o[0], o[1], o[2], o[3]};
            float4 w1 = {o[4], o[5], o[6], o[7]};
            *(float4*)(xg1 + (size_t)node * DIM + d8) = w0;
            *(float4*)(xg1 + (size_t)node * DIM + d8 + 4) = w1;
            half8 oh;
#pragma unroll
            for (int j = 0; j < 8; j++) oh[j] = (_Float16)o[j];
            *(half8*)(xg1h + (size_t)node * DIM + d8) = oh;
        }
    } else {
        if (threadIdx.x >= 64) return;
        int l = b - CONC_B;
        int lane = threadIdx.x;
        int d0 = lane * 2;
        if (l >= LCOM) {
            ushort2 z = {0, 0};
            *(ushort2*)(tyh + (size_t)l * 128 + d0) = z;
            *(ushort2*)(tyl + (size_t)l * 128 + d0) = z;
            return;
        }
        int row = lc[l];
        int s0 = off1[row], s1 = off1[row + 1];
        float2 acc = {0.f, 0.f};
        for (int i = s0; i < s1; i++) {
            int s = elist1[i];
            float2 v = *(const float2*)(emb + (size_t)s * DIM + lane * 2);
            acc.x += v.x; acc.y += v.y;
        }
        float inv = 1.0f / (float)max(s1 - s0, 1);
        float2 e = *(const float2*)(emb + (size_t)row * DIM + lane * 2);
        float v0 = fmaxf(e.x + acc.x * inv, 0.f) * w[d0];
        float v1 = fmaxf(e.y + acc.y * inv, 0.f) * w[d0 + 1];
        unsigned short h0 = f2bf(v0), h1 = f2bf(v1);
        ushort2 hh = {h0, h1};
        ushort2 ll = {f2bf(v0 - bf2f(h0)), f2bf(v1 - bf2f(h1))};
        *(ushort2*)(tyh + (size_t)l * 128 + d0) = hh;
        *(ushort2*)(tyl + (size_t)l * 128 + d0) = ll;
    }
}

// ---------------- rgcn aggregation: fp16 gather, 2-deep row pipeline (matches mean degree 16), fp16 agg out ----------------
__global__ __launch_bounds__(256) void k_rgcn_gather(const _Float16* __restrict__ xh,
                                                     const int* __restrict__ off,
                                                     const int* __restrict__ elist,
                                                     const float* __restrict__ comp,
                                                     _Float16* __restrict__ aggh, int n) {
    __shared__ float scomp[NREL * NB];
    __shared__ float nrmlds[4][NREL];
    if (threadIdx.x < NREL * NB) scomp[threadIdx.x] = comp[threadIdx.x];
    __syncthreads();
    int nb = threadIdx.x >> 6;
    int node = blockIdx.x * 4 + nb;
    int lane = threadIdx.x & 63;
    if (node >= n) return;
    int s0 = off[node], s1 = off[node + 1];
    // prescan: byte-packed per-type counts, lane-parallel then shfl-reduce
    unsigned long long c0 = 0, c1 = 0;
    for (int i = s0 + lane; i < s1; i += 64) {
        int t = elist[i] & 15;
        if (t < 8) c0 += 1ull << (8 * t); else c1 += 1ull << (8 * (t - 8));
    }
#pragma unroll
    for (int o = 32; o; o >>= 1) {
        c0 += __shfl_xor(c0, o, 64);
        c1 += __shfl_xor(c1, o, 64);
    }
    if (lane < NREL) {
        unsigned int c = (lane < 8) ? (unsigned int)((c0 >> (8 * lane)) & 255)
                                    : (unsigned int)((c1 >> (8 * (lane - 8))) & 255);
        nrmlds[nb][lane] = 1.0f / (float)max(c, 1u);
    }
    // same-wave LDS write->read: no barrier needed
    int quad = lane >> 4, d8 = (lane & 15) * 8;
    float a[4][8] = {};
#define RGE(P, GATE)                                                           \
    {                                                                          \
        int s_ = (P) >> 4, t_ = (P) & 15;                                      \
        float nr_ = nrmlds[nb][t_] * (GATE);                                   \
        float4 cf_ = *(const float4*)(scomp + t_ * 4);                         \
        half8 hv_ = *(const half8*)(xh + (size_t)s_ * DIM + d8);               \
        float c0_ = cf_.x * nr_, c1_ = cf_.y * nr_;                            \
        float c2_ = cf_.z * nr_, c3_ = cf_.w * nr_;                            \
        _Pragma("unroll")                                                      \
        for (int j = 0; j < 8; j++) {                                          \
            float v_ = (float)hv_[j];                                          \
            a[0][j] = fmaf(c0_, v_, a[0][j]);                                  \
            a[1][j] = fmaf(c1_, v_, a[1][j]);                                  \
            a[2][j] = fmaf(c2_, v_, a[2][j]);                                  \
            a[3][j] = fmaf(c3_, v_, a[3][j]);                                  \
        }                                                                      \
    }
    int i = s0;
    for (; i + 8 <= s1; i += 8) {
        int pa = elist[i + quad];
        int pb = elist[i + 4 + quad];
        RGE(pa, 1.0f);
        RGE(pb, 1.0f);
    }
    if (i + 4 <= s1) {
        int pa = elist[i + quad];
        RGE(pa, 1.0f);
        i += 4;
    }
    if (i < s1) {
        int e = i + quad;
        bool ok = e < s1;
        int pa = elist[ok ? e : i];
        RGE(pa, ok ? 1.0f : 0.0f);
    }
#undef RGE
#pragma unroll
    for (int bb = 0; bb < 4; bb++)
#pragma unroll
        for (int j = 0; j < 8; j++) {
            a[bb][j] += __shfl_xor(a[bb][j], 16, 64);
            a[bb][j] += __shfl_xor(a[bb][j], 32, 64);
        }
    if (quad == 0) {
        _Float16* o = aggh + (size_t)node * (NB * DIM) + d8;
#pragma unroll
        for (int bb = 0; bb < 4; bb++) {
            half8 hv;
#pragma unroll
            for (int j = 0; j < 8; j++) hv[j] = (_Float16)a[bb][j];
            *(half8*)(o + bb * DIM) = hv;
        }
    }
}

// ---------------- split-precision MFMA GEMM (fp32 x, fp16 agg; optional fp16 shadow out) ----------------
#define LDSK 40
__global__ __launch_bounds__(256) void k_gemm(const float* __restrict__ x,
                                              const _Float16* __restrict__ aggh,
                                              const unsigned short* __restrict__ Wh,
                                              const unsigned short* __restrict__ Wl,
                                              const float* __restrict__ bias,
                                              float* __restrict__ out,
                                              _Float16* __restrict__ out_h, int relu) {
    __shared__ __align__(16) short Ah[128 * LDSK];
    __shared__ __align__(16) short Al[128 * LDSK];
    __shared__ __align__(16) short Bh[128 * LDSK];
    __shared__ __align__(16) short Bl[128 * LDSK];
    int tid = threadIdx.x;
    int lane = tid & 63, wid = tid >> 6;
    int wave_m = wid >> 1, wave_n = wid & 1;
    int l15 = lane & 15, quad = lane >> 4;
    int row0 = blockIdx.x * 128;

    int srow = tid >> 1, skh = (tid & 1) * 16;

    f32x4 acc[4][4] = {};
    for (int k0 = 0; k0 < 640; k0 += 32) {
        {
            int rg = row0 + srow;
            float4 q0 = {0, 0, 0, 0}, q1 = q0, q2 = q0, q3 = q0;
            if (rg < N2) {
                if (k0 < 128) {
                    const float* src = x + (size_t)rg * 128 + k0 + skh;
                    q0 = *(const float4*)(src + 0);
                    q1 = *(const float4*)(src + 4);
                    q2 = *(const float4*)(src + 8);
                    q3 = *(const float4*)(src + 12);
                } else {
                    const _Float16* src = aggh + (size_t)rg * 512 + (k0 - 128) + skh;
                    half8 ha = *(const half8*)(src);
                    half8 hb = *(const half8*)(src + 8);
                    q0 = {(float)ha[0], (float)ha[1], (float)ha[2], (float)ha[3]};
                    q1 = {(float)ha[4], (float)ha[5], (float)ha[6], (float)ha[7]};
                    q2 = {(float)hb[0], (float)hb[1], (float)hb[2], (float)hb[3]};
                    q3 = {(float)hb[4], (float)hb[5], (float)hb[6], (float)hb[7]};
                }
            }
            short8 h0, l0, h1, l1;
            split8(q0, q1, h0, l0);
            split8(q2, q3, h1, l1);
            *(short8*)(&Ah[srow * LDSK + skh]) = h0;
            *(short8*)(&Ah[srow * LDSK + skh + 8]) = h1;
            *(short8*)(&Al[srow * LDSK + skh]) = l0;
            *(short8*)(&Al[srow * LDSK + skh + 8]) = l1;
        }
        {
            const unsigned short* sh = Wh + (size_t)srow * 640 + k0 + skh;
            const unsigned short* sl = Wl + (size_t)srow * 640 + k0 + skh;
            *(short8*)(&Bh[srow * LDSK + skh]) = *(const short8*)(sh);
            *(short8*)(&Bh[srow * LDSK + skh + 8]) = *(const short8*)(sh + 8);
            *(short8*)(&Bl[srow * LDSK + skh]) = *(const short8*)(sl);
            *(short8*)(&Bl[srow * LDSK + skh + 8]) = *(const short8*)(sl + 8);
        }
        __syncthreads();
        short8 ah[4], al[4], bh[4], bl[4];
#pragma unroll
        for (int i = 0; i < 4; i++) {
            int ro = (wave_m * 64 + i * 16 + l15) * LDSK + quad * 8;
            ah[i] = *(const short8*)(&Ah[ro]);
            al[i] = *(const short8*)(&Al[ro]);
        }
#pragma unroll
        for (int j = 0; j < 4; j++) {
            int ro = (wave_n * 64 + j * 16 + l15) * LDSK + quad * 8;
            bh[j] = *(const short8*)(&Bh[ro]);
            bl[j] = *(const short8*)(&Bl[ro]);
        }
#pragma unroll
        for (int i = 0; i < 4; i++)
#pragma unroll
            for (int j = 0; j < 4; j++) {
                acc[i][j] = __builtin_amdgcn_mfma_f32_16x16x32_bf16(al[i], bh[j], acc[i][j], 0, 0, 0);
                acc[i][j] = __builtin_amdgcn_mfma_f32_16x16x32_bf16(ah[i], bl[j], acc[i][j], 0, 0, 0);
                acc[i][j] = __builtin_amdgcn_mfma_f32_16x16x32_bf16(ah[i], bh[j], acc[i][j], 0, 0, 0);
            }
        __syncthreads();
    }
#pragma unroll
    for (int j = 0; j < 4; j++) {
        int gcol = wave_n * 64 + j * 16 + l15;
        float bv = bias[gcol];
#pragma unroll
        for (int i = 0; i < 4; i++) {
            int grow_base = row0 + wave_m * 64 + i * 16 + quad * 4;
#pragma unroll
            for (int r = 0; r < 4; r++) {
                int grow = grow_base + r;
                if (grow >= N2) continue;
                float v = acc[i][j][r] + bv;
                if (relu) v = fmaxf(v, 0.f);
                out[(size_t)grow * 128 + gcol] = v;
                if (out_h) out_h[(size_t)grow * 128 + gcol] = (_Float16)v;
            }
        }
    }
}

// ---------------- logits + softmax: MFMA, no LDS ----------------
__global__ __launch_bounds__(256) void k_logits(const float* __restrict__ h2,
                                                const unsigned short* __restrict__ tyh,
                                                const unsigned short* __restrict__ tyl,
                                                float* __restrict__ out, int M) {
    int wid = threadIdx.x >> 6, lane = threadIdx.x & 63;
    int l15 = lane & 15, quad = lane >> 4;
    int row0w = blockIdx.x * 64 + wid * 16;
    int arow = min(row0w + l15, M - 1);
    f32x4 acc[7] = {};
#pragma unroll
    for (int k0 = 0; k0 < 128; k0 += 32) {
        const float* ap = h2 + (size_t)arow * 128 + k0 + quad * 8;
        float4 q0 = *(const float4*)(ap);
        float4 q1 = *(const float4*)(ap + 4);
        short8 ah, al;
        split8(q0, q1, ah, al);
#pragma unroll
        for (int j = 0; j < 7; j++) {
            size_t bo = (size_t)(j * 16 + l15) * 128 + k0 + quad * 8;
            short8 bh = *(const short8*)(tyh + bo);
            short8 bl = *(const short8*)(tyl + bo);
            acc[j] = __builtin_amdgcn_mfma_f32_16x16x32_bf16(al, bh, acc[j], 0, 0, 0);
            acc[j] = __builtin_amdgcn_mfma_f32_16x16x32_bf16(ah, bl, acc[j], 0, 0, 0);
            acc[j] = __builtin_amdgcn_mfma_f32_16x16x32_bf16(ah, bh, acc[j], 0, 0, 0);
        }
    }
    bool v6 = (l15 < LCOM - 96);
#pragma unroll
    for (int r = 0; r < 4; r++) {
        int grow = row0w + quad * 4 + r;
        float m = -INFINITY;
#pragma unroll
        for (int j = 0; j < 6; j++) m = fmaxf(m, acc[j][r]);
        if (v6) m = fmaxf(m, acc[6][r]);
        m = fmaxf(m, __shfl_xor(m, 8, 64));
        m = fmaxf(m, __shfl_xor(m, 4, 64));
        m = fmaxf(m, __shfl_xor(m, 2, 64));
        m = fmaxf(m, __shfl_xor(m, 1, 64));
        float e[7];
        float s = 0.f;
#pragma unroll
        for (int j = 0; j < 6; j++) { e[j] = __expf(acc[j][r] - m); s += e[j]; }
        e[6] = v6 ? __expf(acc[6][r] - m) : 0.f;
        s += e[6];
        s += __shfl_xor(s, 8, 64);
        s += __shfl_xor(s, 4, 64);
        s += __shfl_xor(s, 2, 64);
        s += __shfl_xor(s, 1, 64);
        float inv = 1.0f / s;
        if (grow < M) {
#pragma unroll
            for (int j = 0; j < 6; j++) out[(size_t)grow * LCOM + j * 16 + l15] = e[j] * inv;
            if (v6) out[(size_t)grow * LCOM + 96 + l15] = e[6] * inv;
        }
    }
}

extern "C" void kernel_launch(void* const* d_in, const int* in_sizes, int n_in,
                              void* d_out, int out_size, void* d_ws, size_t ws_size,
                              hipStream_t stream) {
    const int* ei2 = (const int*)d_in[0];
    const int* et2 = (const int*)d_in[1];
    const int* ei1 = (const int*)d_in[2];
    const int* lc = (const int*)d_in[3];
    const float* emb = (const float*)d_in[4];
    const float* basis1 = (const float*)d_in[5];
    const float* comp1 = (const float*)d_in[6];
    const float* root1 = (const float*)d_in[7];
    const float* bias1 = (const float*)d_in[8];
    const float* basis2 = (const float*)d_in[9];
    const float* comp2 = (const float*)d_in[10];
    const float* root2 = (const float*)d_in[11];
    const float* bias2 = (const float*)d_in[12];
    const float* wts = (const float*)d_in[13];
    float* out = (float*)d_out;
    int E2 = in_sizes[0] / 2, E1 = in_sizes[2] / 2;

    float* ws = (float*)d_ws;
    float* xg1 = ws;                          // 6,400,000 f (reused as h2)
    float* h1 = xg1 + 6400000;                // 6,400,000 f (first half aliased as xg1_h)
    float* agg = h1 + 6400000;                // 25,600,000 f (head: deg slices pre-scatter, then fp16 agg)
    _Float16* emb_h = (_Float16*)(agg + 25600000);  // 7,680,000 h (first 6.4M aliased as h1_h)
    unsigned short* tyh = (unsigned short*)(emb_h + 7680000);  // 14,336
    unsigned short* tyl = tyh + LPAD * 128;                    // 14,336
    unsigned short* Wh1 = tyl + LPAD * 128;   // 81,920 each
    unsigned short* Wl1 = Wh1 + 81920;
    unsigned short* Wh2 = Wl1 + 81920;
    unsigned short* Wl2 = Wh2 + 81920;
    int* ipool = (int*)(Wl2 + 81920);
    int* deg1 = ipool;                        // 60,000 (compact, written by p1m)
    int* deg2 = deg1 + 60000;                 // 50,000
    int* off1 = deg2 + 50000;                 // 60,001
    int* elist1 = off1 + 60001;               // 800,000
    int* off2 = elist1 + 800000;              // 50,001
    int* elist2 = off2 + 50001;               // 800,000
    int* bsum1 = elist2 + 800000;             // 64
    int* boff1 = bsum1 + 64;
    int* bsum2 = boff1 + 64;
    int* boff2 = bsum2 + 64;
    int* degs1 = (int*)agg;                   // NC*60,000 slice hist -> slice bases
    int* degs2 = degs1 + NC * N1;             // NC*50,000 (28.2 MB, dead after k_scat)
    _Float16* agg_h = (_Float16*)agg;         // fp16 agg (25.6 MB), written by gather after scat
    _Float16* xg1_h = (_Float16*)h1;          // alias: gather1 consumes xg1_h before gemm1 writes h1
    _Float16* h1_h = emb_h;                   // alias: emb_h consumed by k_mix before gemm1 writes
    float* h2 = xg1;                          // alias: xg1 dead after gemm1

    const int NB1 = (N1 + 1023) / 1024;       // 59
    const int NB2 = (N2 + 1023) / 1024;       // 49
    const int PB = (2 * 640 * 128) / 256;     // 640
    const int CB = (N1 * DIM / 4 + 255) / 256;  // 7500
    const int CONC_B = (N2 + 3) / 4;          // 12500

    // 1) prelude: atomic-free slice hists (dispatch first) ∪ weight prep ∪ emb cast
    k_prelude<<<2 * NPART * NC + PB + CB, 256, 0, stream>>>(
        ei1, E1, degs1, ei2, E2, degs2,
        root1, basis1, Wh1, Wl1, root2, basis2, Wh2, Wl2, PB,
        emb, emb_h, N1 * DIM / 4);

    // 2-4) merged scans (p1 sums slices -> compact deg; p3 writes off + converts slices to bases)
    k_scan_p1m<<<NB1 + NB2, 256, 0, stream>>>(degs1, deg1, N1, NB1, bsum1,
                                              degs2, deg2, N2, bsum2);
    k_scan_p2m<<<2, 64, 0, stream>>>(bsum1, boff1, off1, NB1, N1, bsum2, boff2, off2, NB2, N2);
    k_scan_p3m<<<NB1 + NB2, 256, 0, stream>>>(deg1, boff1, off1, degs1, N1, NB1,
                                              deg2, boff2, off2, degs2, N2);

    // 5) atomic-free scatter, both graphs (exact positions, plain stores)
    k_scat<<<2 * NPART * NC, 256, 0, stream>>>(ei1, E1, degs1, elist1,
                                               ei2, et2, E2, degs2, elist2);

    // 6) mix: concept ∪ tyw
    k_mix<<<CONC_B + LPAD, 256, 0, stream>>>(
        emb_h, emb, off1, elist1, xg1, xg1_h, CONC_B,
        lc, wts, tyh, tyl);

    // 7-8) rgcn layer 1 (fp16 agg)
    k_rgcn_gather<<<CONC_B, 256, 0, stream>>>(xg1_h, off2, elist2, comp1, agg_h, N2);
    k_gemm<<<(N2 + 127) / 128, 256, 0, stream>>>(xg1, agg_h, Wh1, Wl1, bias1, h1, h1_h, 1);

    // 9-10) rgcn layer 2 (fp16 agg)
    k_rgcn_gather<<<CONC_B, 256, 0, stream>>>(h1_h, off2, elist2, comp2, agg_h, N2);
    k_gemm<<<(N2 + 127) / 128, 256, 0, stream>>>(h1, agg_h, Wh2, Wl2, bias2, h2, (_Float16*)nullptr, 0);

    // 11) logits + softmax
    k_logits<<<(N2 + 63) / 64, 256, 0, stream>>>(h2, tyh, tyl, out, N2);
}